// Round 8
// baseline (197.189 us; speedup 1.0000x reference)
//
#include <hip/hip_runtime.h>
#include <hip/hip_bf16.h>
#include <stdint.h>
#include <stddef.h>

typedef unsigned short u16;
typedef unsigned int   u32;
typedef __attribute__((ext_vector_type(8))) short bf16x8;  // 8 bf16 = 4 VGPRs
typedef __attribute__((ext_vector_type(4))) float f32x4;   // MFMA C/D

#define LOG2E   1.44269504f
#define EXP_OFF 23.0831206f   // 16 * log2(e)

static __device__ __forceinline__ float bf2f(u16 v) {
    u32 u = ((u32)v) << 16; float f; __builtin_memcpy(&f, &u, 4); return f;
}
static __device__ __forceinline__ u16 f2bf(float f) {
    u32 u; __builtin_memcpy(&u, &f, 4);
    u32 r = (u + 0x7fffu + ((u >> 16) & 1u)) >> 16; return (u16)r;
}
static __device__ __forceinline__ float as_f(u32 u) { float f; __builtin_memcpy(&f, &u, 4); return f; }
static __device__ __forceinline__ u32   as_u(float f) { u32 u; __builtin_memcpy(&u, &f, 4); return u; }

// fp32-vs-bf16 input detection (wave 0)
static __device__ __forceinline__ int detect_f32_wave0(const void* x, int t) {
    const u32* xw = (const u32*)x;
    int bad = 0;
    #pragma unroll
    for (int k = 0; k < 4; ++k) {
        u32 wv = xw[(t << 2) + k];
        int e = (wv >> 7) & 0xff;
        bad += (e >= 160);
    }
    unsigned long long m = __ballot(bad > 0);
    return (__popcll(m) >= 8) ? 1 : 0;
}

// ---------------------------------------------------------------------------
// Kernel 1 (r3's proven scalar proj; flash-required layouts):
//   qws [n][i][32]  bf16, pre-scaled by log2(e)
//   kws [n][i][32]  bf16
//   vws [n][c][i]   bf16 channel-major
// ---------------------------------------------------------------------------
__global__ __launch_bounds__(256) void qkv_proj_kernel(
    const void* __restrict__ x,
    const void* __restrict__ Wq, const void* __restrict__ bq,
    const void* __restrict__ Wk, const void* __restrict__ bk,
    const void* __restrict__ Wv, const void* __restrict__ bv,
    u16* __restrict__ qws, u16* __restrict__ kws, u16* __restrict__ vws,
    int n_off)
{
    __shared__ float Ws[32][68];
    __shared__ float Xs[32][68];
    __shared__ int dtf;

    const int t   = threadIdx.x;
    const int it  = blockIdx.x;
    const int ot  = blockIdx.y;
    const int n_w = blockIdx.z;
    const int n_g = n_off + n_w;
    const int i0  = it << 6;
    const int tx  = t & 15;
    const int ty  = t >> 4;

    if (t < 64) { int f = detect_f32_wave0(x, t); if (t == 0) dtf = f; }
    __syncthreads();
    const bool isf32 = (dtf != 0);

    float acc[4][4];
    #pragma unroll
    for (int a = 0; a < 4; ++a)
        #pragma unroll
        for (int b = 0; b < 4; ++b) acc[a][b] = 0.f;

    const int o_st   = t & 63;
    const int kk0    = (t >> 6) << 3;
    const int och_st = (ot << 6) + o_st;
    int wsel, wrow;
    if (och_st < 32)      { wsel = 0; wrow = och_st; }
    else if (och_st < 64) { wsel = 1; wrow = och_st - 32; }
    else                  { wsel = 2; wrow = och_st - 64; }
    const void* wbase = (wsel == 0) ? Wq : (wsel == 1) ? Wk : Wv;

    for (int c0 = 0; c0 < 256; c0 += 32) {
        if (isf32) {
            const float* wf = (const float*)wbase + wrow * 256 + c0 + kk0;
            #pragma unroll
            for (int k8 = 0; k8 < 8; ++k8) Ws[kk0 + k8][o_st] = wf[k8];
            const float* xf = (const float*)x;
            #pragma unroll
            for (int v = 0; v < 2; ++v) {
                int g  = t + (v << 8);
                int kk = g >> 4;
                int ii = (g & 15) << 2;
                float4 x4 = *(const float4*)(xf +
                    (((size_t)(n_g * 256 + c0 + kk)) << 12) + i0 + ii);
                Xs[kk][ii + 0] = x4.x; Xs[kk][ii + 1] = x4.y;
                Xs[kk][ii + 2] = x4.z; Xs[kk][ii + 3] = x4.w;
            }
        } else {
            const u16* wh = (const u16*)wbase + wrow * 256 + c0 + kk0;
            #pragma unroll
            for (int k8 = 0; k8 < 8; ++k8) Ws[kk0 + k8][o_st] = bf2f(wh[k8]);
            const u16* xh = (const u16*)x;
            #pragma unroll
            for (int v = 0; v < 2; ++v) {
                int g  = t + (v << 8);
                int kk = g >> 4;
                int ii = (g & 15) << 2;
                ushort4 u4 = *(const ushort4*)(xh +
                    (((size_t)(n_g * 256 + c0 + kk)) << 12) + i0 + ii);
                Xs[kk][ii + 0] = bf2f(u4.x); Xs[kk][ii + 1] = bf2f(u4.y);
                Xs[kk][ii + 2] = bf2f(u4.z); Xs[kk][ii + 3] = bf2f(u4.w);
            }
        }
        __syncthreads();

        #pragma unroll
        for (int kk = 0; kk < 32; ++kk) {
            float4 a4 = *(const float4*)&Ws[kk][ty << 2];
            float4 b4 = *(const float4*)&Xs[kk][tx << 2];
            float av[4] = {a4.x, a4.y, a4.z, a4.w};
            float bw[4] = {b4.x, b4.y, b4.z, b4.w};
            #pragma unroll
            for (int a = 0; a < 4; ++a)
                #pragma unroll
                for (int b = 0; b < 4; ++b)
                    acc[a][b] += av[a] * bw[b];
        }
        __syncthreads();
    }

    #pragma unroll
    for (int a = 0; a < 4; ++a) {
        int och = (ot << 6) + (ty << 2) + a;
        float bias;
        if (isf32) {
            if (och < 32)      bias = ((const float*)bq)[och];
            else if (och < 64) bias = ((const float*)bk)[och - 32];
            else               bias = ((const float*)bv)[och - 64];
        } else {
            if (och < 32)      bias = bf2f(((const u16*)bq)[och]);
            else if (och < 64) bias = bf2f(((const u16*)bk)[och - 32]);
            else               bias = bf2f(((const u16*)bv)[och - 64]);
        }
        if (och < 32) {
            #pragma unroll
            for (int b = 0; b < 4; ++b) {
                int i = i0 + (tx << 2) + b;
                qws[(((size_t)(n_w << 12) + i) << 5) + och] =
                    f2bf((acc[a][b] + bias) * LOG2E);
            }
        } else if (och < 64) {
            #pragma unroll
            for (int b = 0; b < 4; ++b) {
                int i = i0 + (tx << 2) + b;
                kws[(((size_t)(n_w << 12) + i) << 5) + (och - 32)] =
                    f2bf(acc[a][b] + bias);
            }
        } else {
            ushort4 h;
            h.x = f2bf(acc[a][0] + bias);
            h.y = f2bf(acc[a][1] + bias);
            h.z = f2bf(acc[a][2] + bias);
            h.w = f2bf(acc[a][3] + bias);
            *(ushort4*)(vws + (((size_t)n_w) << 20)
                        + ((size_t)(och - 64) << 12) + i0 + (tx << 2)) = h;
        }
    }
}

// ---------------------------------------------------------------------------
// Kernel 2 (v8): PV-lag single-barrier flash, V fragments DIRECT FROM GLOBAL
// (chan-major V; B-frag = 16B contiguous load; L2-served via batch<->XCD
// affinity). LDS holds only double-buffered Ps (16 KB) + aliased Dbuf.
// S: wave (qsub_s 0..3, jsub 0..3) -> 1 MFMA. PV: wave (cq 0..7 -> 32c,
// jq 0..1 -> 32j): pa[4] from LDS, vf[2] from global, 8 MFMAs.
// NO min-occupancy launch bound (r6 spill lesson).
// ---------------------------------------------------------------------------
__global__ __launch_bounds__(1024) void flash_mfma5(
    const u16* __restrict__ qws, const u16* __restrict__ kws,
    const u16* __restrict__ vws, void* __restrict__ out,
    const void* __restrict__ x, int n_off, int nshift)
{
    // arena: [2][64*64] u16 Ps (16 KB); epilogue aliases Dbuf (64*68 f32).
    __shared__ __align__(16) char arena[17920];
    __shared__ __align__(16) float lS[64];
    __shared__ int dtf;
    u16*   PsA  = (u16*)arena;                 // + par*4096 (elems)
    float* Dbuf = (float*)arena;               // epilogue alias

    const int t    = threadIdx.x;
    const int lane = t & 63;
    const int w    = t >> 6;          // 0..15
    const int n16  = lane & 15;
    const int quad = lane >> 4;
    const int bid  = blockIdx.x;
    const int n_w  = bid & ((1 << nshift) - 1);
    const int qt   = bid >> nshift;
    const int n_g  = n_off + n_w;
    const int i0   = qt << 6;

    if (t < 64) {
        int f = detect_f32_wave0(x, t);
        if (t == 0) dtf = f;
        lS[t] = 0.f;
    }

    const u16* qb = qws + (((size_t)n_w) << 17);
    const u16* kb = kws + (((size_t)n_w) << 17);
    const u16* vb = vws + (((size_t)n_w) << 20);

    // S decomposition
    const int qsub_s = w & 3;
    const int jsub   = w >> 2;
    // PV decomposition: 32 c x 32 j per wave (no V-frag duplication)
    const int cq = w & 7;
    const int jq = w >> 3;

    const bf16x8 qfrag =
        *(const bf16x8*)(qb + ((size_t)(i0 + (qsub_s << 4) + n16) << 5) + (quad << 3));

    f32x4 acc[4][2];
    #pragma unroll
    for (int a = 0; a < 4; ++a)
        #pragma unroll
        for (int b = 0; b < 2; ++b) acc[a][b] = (f32x4){0.f, 0.f, 0.f, 0.f};
    float lp[4] = {0.f, 0.f, 0.f, 0.f};

    const int jcol = (jsub << 4) + n16;
    const int j8   = jcol >> 3;
    const int jlo  = jcol & 7;
    const int ksw  = (jq << 2) + quad;

    // V fragment base addresses (chan-major): row c = cq*32 + cs*16 + n16,
    // byte col = j0 + jq*32 + quad*8
    const u16* vfp0 = vb + (size_t)((cq << 5) + n16) * 4096 + (jq << 5) + (quad << 3);
    const u16* vfp1 = vfp0 + (size_t)16 * 4096;

    bf16x8 kreg, vf0, vf1;

    // ---- prologue: S(0) into parity 0; prefetch K(1) and V-frags for PV(0) ----
    kreg = *(const bf16x8*)(kb + ((size_t)((jsub << 4) + n16) << 5) + (quad << 3));
    {
        u16* Ps = PsA;
        const f32x4 z = {0.f, 0.f, 0.f, 0.f};
        f32x4 s = __builtin_amdgcn_mfma_f32_16x16x32_bf16(qfrag, kreg, z, 0, 0, 0);
        #pragma unroll
        for (int r = 0; r < 4; ++r) {
            const int qrow = (qsub_s << 4) + (quad << 2) + r;
            float p = exp2f(s[r] - EXP_OFF);
            u32 u = as_u(p) & 0xffff0000u;
            lp[r] += as_f(u);
            Ps[qrow * 64 + ((j8 ^ (qrow & 7)) << 3) + jlo] = (u16)(u >> 16);
        }
        kreg = *(const bf16x8*)(kb + ((size_t)(64 + (jsub << 4) + n16) << 5) + (quad << 3));
        vf0 = *(const bf16x8*)(vfp0);
        vf1 = *(const bf16x8*)(vfp1);
    }
    __syncthreads();

    // ---- main loop: ONE barrier per tile ----
    for (int tile = 1; tile < 64; ++tile) {
        const int par  = tile & 1;
        u16* Psc = PsA + (par << 12);
        u16* Psp = PsA + ((par ^ 1) << 12);

        // PV(tile-1): pa from LDS, vf from prefetched global regs
        bf16x8 pa[4];
        #pragma unroll
        for (int qs = 0; qs < 4; ++qs) {
            const int qrow = (qs << 4) + n16;
            pa[qs] = *(const bf16x8*)&Psp[qrow * 64 + ((ksw ^ (qrow & 7)) << 3)];
        }
        #pragma unroll
        for (int qs = 0; qs < 4; ++qs) {
            acc[qs][0] = __builtin_amdgcn_mfma_f32_16x16x32_bf16(pa[qs], vf0, acc[qs][0], 0, 0, 0);
            acc[qs][1] = __builtin_amdgcn_mfma_f32_16x16x32_bf16(pa[qs], vf1, acc[qs][1], 0, 0, 0);
        }

        // prefetch V-frags for PV(tile) (used next iteration)
        vf0 = *(const bf16x8*)(vfp0 + (tile << 6));
        vf1 = *(const bf16x8*)(vfp1 + (tile << 6));

        // S(tile) + softmax + P write
        const f32x4 z = {0.f, 0.f, 0.f, 0.f};
        f32x4 s = __builtin_amdgcn_mfma_f32_16x16x32_bf16(qfrag, kreg, z, 0, 0, 0);
        #pragma unroll
        for (int r = 0; r < 4; ++r) {
            const int qrow = (qsub_s << 4) + (quad << 2) + r;
            float p = exp2f(s[r] - EXP_OFF);
            u32 u = as_u(p) & 0xffff0000u;
            lp[r] += as_f(u);
            Psc[qrow * 64 + ((j8 ^ (qrow & 7)) << 3) + jlo] = (u16)(u >> 16);
        }

        // prefetch K for tile+1
        if (tile < 63) {
            const int j0n = (tile + 1) << 6;
            kreg = *(const bf16x8*)(kb + ((size_t)(j0n + (jsub << 4) + n16) << 5)
                                    + (quad << 3));
        }
        __syncthreads();
    }

    // ---- final PV(63): parity 1, vf holds j=63*64 ----
    {
        u16* Psp = PsA + (1 << 12);
        bf16x8 pa[4];
        #pragma unroll
        for (int qs = 0; qs < 4; ++qs) {
            const int qrow = (qs << 4) + n16;
            pa[qs] = *(const bf16x8*)&Psp[qrow * 64 + ((ksw ^ (qrow & 7)) << 3)];
        }
        #pragma unroll
        for (int qs = 0; qs < 4; ++qs) {
            acc[qs][0] = __builtin_amdgcn_mfma_f32_16x16x32_bf16(pa[qs], vf0, acc[qs][0], 0, 0, 0);
            acc[qs][1] = __builtin_amdgcn_mfma_f32_16x16x32_bf16(pa[qs], vf1, acc[qs][1], 0, 0, 0);
        }
    }

    // ---- l reduction ----
    #pragma unroll
    for (int r = 0; r < 4; ++r) {
        lp[r] += __shfl_xor(lp[r], 1);
        lp[r] += __shfl_xor(lp[r], 2);
        lp[r] += __shfl_xor(lp[r], 4);
        lp[r] += __shfl_xor(lp[r], 8);
    }
    if (n16 == 0) {
        #pragma unroll
        for (int r = 0; r < 4; ++r)
            atomicAdd(&lS[(qsub_s << 4) + (quad << 2) + r], lp[r]);
    }
    __syncthreads();
    if (t < 64) lS[t] = 1.0f / lS[t];
    const bool isf32 = (dtf != 0);

    // ---- epilogue: 4 chunks of 64 c; combine jq-partials in Dbuf, store ----
    for (int chunk = 0; chunk < 4; ++chunk) {
        __syncthreads();   // Dbuf free; rl ready; Ps reads complete (chunk 0)
        if (jq == 1 && (cq >> 1) == chunk) {
            #pragma unroll
            for (int qs = 0; qs < 4; ++qs)
                #pragma unroll
                for (int cs = 0; cs < 2; ++cs)
                    *(f32x4*)&Dbuf[(((cq & 1) << 5) + (cs << 4) + n16) * 68 +
                                   (qs << 4) + (quad << 2)] = acc[qs][cs];
        }
        __syncthreads();
        if (jq == 0 && (cq >> 1) == chunk) {
            #pragma unroll
            for (int qs = 0; qs < 4; ++qs)
                #pragma unroll
                for (int cs = 0; cs < 2; ++cs) {
                    float* p = &Dbuf[(((cq & 1) << 5) + (cs << 4) + n16) * 68 +
                                     (qs << 4) + (quad << 2)];
                    f32x4 d = *(f32x4*)p;
                    d += acc[qs][cs];
                    *(f32x4*)p = d;
                }
        }
        __syncthreads();
        // store: 1024 threads x 4 q
        const int c_l = t >> 4;
        const int qg  = (t & 15) << 2;
        float4 d  = *(float4*)&Dbuf[c_l * 68 + qg];
        float4 rl = *(float4*)&lS[qg];
        const int c_glob = (chunk << 6) + c_l;
        const size_t ob = (((size_t)(n_g * 256 + c_glob)) << 12) + i0 + qg;
        if (isf32) {
            float4 o = make_float4(d.x * rl.x, d.y * rl.y, d.z * rl.z, d.w * rl.w);
            *(float4*)((float*)out + ob) = o;
        } else {
            union { uint2 v; u16 h[4]; } o;
            o.h[0] = f2bf(d.x * rl.x);
            o.h[1] = f2bf(d.y * rl.y);
            o.h[2] = f2bf(d.z * rl.z);
            o.h[3] = f2bf(d.w * rl.w);
            *(uint2*)((u16*)out + ob) = o.v;
        }
    }
}

extern "C" void kernel_launch(void* const* d_in, const int* in_sizes, int n_in,
                              void* d_out, int out_size, void* d_ws, size_t ws_size,
                              hipStream_t stream)
{
    const void* x  = d_in[0];
    const void* Wq = d_in[1];
    const void* bq = d_in[2];
    const void* Wk = d_in[3];
    const void* bk = d_in[4];
    const void* Wv = d_in[5];
    const void* bv = d_in[6];

    const size_t full_need = (size_t)(4u * 4096u) * (32 + 32 + 256) * 2; // 10 MB
    if (ws_size >= full_need) {
        u16* qws = (u16*)d_ws;
        u16* kws = qws + (size_t)4 * 4096 * 32;
        u16* vws = kws + (size_t)4 * 4096 * 32;
        qkv_proj_kernel<<<dim3(64, 5, 4), dim3(256), 0, stream>>>(
            x, Wq, bq, Wk, bk, Wv, bv, qws, kws, vws, 0);
        flash_mfma5<<<dim3(256), dim3(1024), 0, stream>>>(
            qws, kws, vws, d_out, x, 0, 2);
    } else {
        u16* qws = (u16*)d_ws;
        u16* kws = qws + (size_t)4096 * 32;
        u16* vws = kws + (size_t)4096 * 32;
        for (int n = 0; n < 4; ++n) {
            qkv_proj_kernel<<<dim3(64, 5, 1), dim3(256), 0, stream>>>(
                x, Wq, bq, Wk, bk, Wv, bv, qws, kws, vws, n);
            flash_mfma5<<<dim3(64), dim3(1024), 0, stream>>>(
                qws, kws, vws, d_out, x, n, 0);
        }
    }
}

// Round 9
// 163.768 us; speedup vs baseline: 1.2041x; 1.2041x over previous
//
#include <hip/hip_runtime.h>
#include <hip/hip_bf16.h>
#include <stdint.h>
#include <stddef.h>

typedef unsigned short u16;
typedef unsigned int   u32;
typedef __attribute__((ext_vector_type(8))) short bf16x8;  // 8 bf16 = 4 VGPRs
typedef __attribute__((ext_vector_type(4))) float f32x4;   // MFMA C/D

#define LOG2E   1.44269504f
#define EXP_OFF 23.0831206f   // 16 * log2(e)

static __device__ __forceinline__ float bf2f(u16 v) {
    u32 u = ((u32)v) << 16; float f; __builtin_memcpy(&f, &u, 4); return f;
}
static __device__ __forceinline__ u16 f2bf(float f) {
    u32 u; __builtin_memcpy(&u, &f, 4);
    u32 r = (u + 0x7fffu + ((u >> 16) & 1u)) >> 16; return (u16)r;
}
static __device__ __forceinline__ float as_f(u32 u) { float f; __builtin_memcpy(&f, &u, 4); return f; }
static __device__ __forceinline__ u32   as_u(float f) { u32 u; __builtin_memcpy(&u, &f, 4); return u; }

// fp32-vs-bf16 input detection (wave 0)
static __device__ __forceinline__ int detect_f32_wave0(const void* x, int t) {
    const u32* xw = (const u32*)x;
    int bad = 0;
    #pragma unroll
    for (int k = 0; k < 4; ++k) {
        u32 wv = xw[(t << 2) + k];
        int e = (wv >> 7) & 0xff;
        bad += (e >= 160);
    }
    unsigned long long m = __ballot(bad > 0);
    return (__popcll(m) >= 8) ? 1 : 0;
}

// V workspace layout (pre-fragmented for MFMA B-operand, per batch):
//   elem_addr = cblk*65536 + jblk*512 + (quad4*16 + clo)*8 + jlo
//   where c = cblk*16 + clo, j = jblk*32 + quad4*8 + jlo.
// A wave B-frag load (lane = quad*16+n16 reads 16B) is 1KB fully contiguous.

// ---------------------------------------------------------------------------
// Kernel 1 (proven scalar proj, ~22us floor):
//   qws [n][i][32]  bf16, pre-scaled by log2(e)
//   kws [n][i][32]  bf16
//   vws pre-fragmented (layout above)
// ---------------------------------------------------------------------------
__global__ __launch_bounds__(256) void qkv_proj_kernel(
    const void* __restrict__ x,
    const void* __restrict__ Wq, const void* __restrict__ bq,
    const void* __restrict__ Wk, const void* __restrict__ bk,
    const void* __restrict__ Wv, const void* __restrict__ bv,
    u16* __restrict__ qws, u16* __restrict__ kws, u16* __restrict__ vws,
    int n_off)
{
    __shared__ float Ws[32][68];
    __shared__ float Xs[32][68];
    __shared__ int dtf;

    const int t   = threadIdx.x;
    const int it  = blockIdx.x;
    const int ot  = blockIdx.y;
    const int n_w = blockIdx.z;
    const int n_g = n_off + n_w;
    const int i0  = it << 6;
    const int tx  = t & 15;
    const int ty  = t >> 4;

    if (t < 64) { int f = detect_f32_wave0(x, t); if (t == 0) dtf = f; }
    __syncthreads();
    const bool isf32 = (dtf != 0);

    float acc[4][4];
    #pragma unroll
    for (int a = 0; a < 4; ++a)
        #pragma unroll
        for (int b = 0; b < 4; ++b) acc[a][b] = 0.f;

    const int o_st   = t & 63;
    const int kk0    = (t >> 6) << 3;
    const int och_st = (ot << 6) + o_st;
    int wsel, wrow;
    if (och_st < 32)      { wsel = 0; wrow = och_st; }
    else if (och_st < 64) { wsel = 1; wrow = och_st - 32; }
    else                  { wsel = 2; wrow = och_st - 64; }
    const void* wbase = (wsel == 0) ? Wq : (wsel == 1) ? Wk : Wv;

    for (int c0 = 0; c0 < 256; c0 += 32) {
        if (isf32) {
            const float* wf = (const float*)wbase + wrow * 256 + c0 + kk0;
            #pragma unroll
            for (int k8 = 0; k8 < 8; ++k8) Ws[kk0 + k8][o_st] = wf[k8];
            const float* xf = (const float*)x;
            #pragma unroll
            for (int v = 0; v < 2; ++v) {
                int g  = t + (v << 8);
                int kk = g >> 4;
                int ii = (g & 15) << 2;
                float4 x4 = *(const float4*)(xf +
                    (((size_t)(n_g * 256 + c0 + kk)) << 12) + i0 + ii);
                Xs[kk][ii + 0] = x4.x; Xs[kk][ii + 1] = x4.y;
                Xs[kk][ii + 2] = x4.z; Xs[kk][ii + 3] = x4.w;
            }
        } else {
            const u16* wh = (const u16*)wbase + wrow * 256 + c0 + kk0;
            #pragma unroll
            for (int k8 = 0; k8 < 8; ++k8) Ws[kk0 + k8][o_st] = bf2f(wh[k8]);
            const u16* xh = (const u16*)x;
            #pragma unroll
            for (int v = 0; v < 2; ++v) {
                int g  = t + (v << 8);
                int kk = g >> 4;
                int ii = (g & 15) << 2;
                ushort4 u4 = *(const ushort4*)(xh +
                    (((size_t)(n_g * 256 + c0 + kk)) << 12) + i0 + ii);
                Xs[kk][ii + 0] = bf2f(u4.x); Xs[kk][ii + 1] = bf2f(u4.y);
                Xs[kk][ii + 2] = bf2f(u4.z); Xs[kk][ii + 3] = bf2f(u4.w);
            }
        }
        __syncthreads();

        #pragma unroll
        for (int kk = 0; kk < 32; ++kk) {
            float4 a4 = *(const float4*)&Ws[kk][ty << 2];
            float4 b4 = *(const float4*)&Xs[kk][tx << 2];
            float av[4] = {a4.x, a4.y, a4.z, a4.w};
            float bw[4] = {b4.x, b4.y, b4.z, b4.w};
            #pragma unroll
            for (int a = 0; a < 4; ++a)
                #pragma unroll
                for (int b = 0; b < 4; ++b)
                    acc[a][b] += av[a] * bw[b];
        }
        __syncthreads();
    }

    #pragma unroll
    for (int a = 0; a < 4; ++a) {
        int och = (ot << 6) + (ty << 2) + a;
        float bias;
        if (isf32) {
            if (och < 32)      bias = ((const float*)bq)[och];
            else if (och < 64) bias = ((const float*)bk)[och - 32];
            else               bias = ((const float*)bv)[och - 64];
        } else {
            if (och < 32)      bias = bf2f(((const u16*)bq)[och]);
            else if (och < 64) bias = bf2f(((const u16*)bk)[och - 32]);
            else               bias = bf2f(((const u16*)bv)[och - 64]);
        }
        if (och < 32) {
            #pragma unroll
            for (int b = 0; b < 4; ++b) {
                int i = i0 + (tx << 2) + b;
                qws[(((size_t)(n_w << 12) + i) << 5) + och] =
                    f2bf((acc[a][b] + bias) * LOG2E);
            }
        } else if (och < 64) {
            #pragma unroll
            for (int b = 0; b < 4; ++b) {
                int i = i0 + (tx << 2) + b;
                kws[(((size_t)(n_w << 12) + i) << 5) + (och - 32)] =
                    f2bf(acc[a][b] + bias);
            }
        } else {
            // V store: pre-fragmented layout. 4 consecutive j (=i) stay
            // within one 8-chunk, so ushort4 remains contiguous.
            const int c = och - 64;
            const int i = i0 + (tx << 2);
            ushort4 h;
            h.x = f2bf(acc[a][0] + bias);
            h.y = f2bf(acc[a][1] + bias);
            h.z = f2bf(acc[a][2] + bias);
            h.w = f2bf(acc[a][3] + bias);
            const size_t addr = ((size_t)n_w << 20)
                + ((size_t)(c >> 4) << 16)          // cblk*65536
                + ((size_t)(i >> 5) << 9)           // jblk*512
                + (size_t)((((((i & 31) >> 3) << 4) + (c & 15)) << 3) + (i & 7));
            *(ushort4*)(vws + addr) = h;
        }
    }
}

// ---------------------------------------------------------------------------
// Kernel 2 (v9): single-barrier PV-lag flash; V fragments direct from global
// in PRE-FRAGMENTED layout (1KB coalesced wave loads, L2-served via
// batch<->XCD affinity). LDS = double-buffered Ps only (+Dbuf alias).
// S: wave (qsub_s 0..3, jsub 0..3). PV: wave (cq 0..7 -> 32c, jq 0..1 -> 32j).
// NO min-occupancy launch bound (r6 spill lesson).
// ---------------------------------------------------------------------------
__global__ __launch_bounds__(1024) void flash_mfma6(
    const u16* __restrict__ qws, const u16* __restrict__ kws,
    const u16* __restrict__ vws, void* __restrict__ out,
    const void* __restrict__ x, int n_off, int nshift)
{
    __shared__ __align__(16) char arena[17920];
    __shared__ __align__(16) float lS[64];
    __shared__ int dtf;
    u16*   PsA  = (u16*)arena;                 // + par*4096 (elems)
    float* Dbuf = (float*)arena;               // epilogue alias

    const int t    = threadIdx.x;
    const int lane = t & 63;
    const int w    = t >> 6;          // 0..15
    const int n16  = lane & 15;
    const int quad = lane >> 4;
    const int bid  = blockIdx.x;
    const int n_w  = bid & ((1 << nshift) - 1);
    const int qt   = bid >> nshift;
    const int n_g  = n_off + n_w;
    const int i0   = qt << 6;

    if (t < 64) {
        int f = detect_f32_wave0(x, t);
        if (t == 0) dtf = f;
        lS[t] = 0.f;
    }

    const u16* qb = qws + (((size_t)n_w) << 17);
    const u16* kb = kws + (((size_t)n_w) << 17);
    const u16* vb = vws + (((size_t)n_w) << 20);

    // S decomposition
    const int qsub_s = w & 3;
    const int jsub   = w >> 2;
    // PV decomposition: 32 c x 32 j per wave
    const int cq = w & 7;
    const int jq = w >> 3;

    const bf16x8 qfrag =
        *(const bf16x8*)(qb + ((size_t)(i0 + (qsub_s << 4) + n16) << 5) + (quad << 3));

    f32x4 acc[4][2];
    #pragma unroll
    for (int a = 0; a < 4; ++a)
        #pragma unroll
        for (int b = 0; b < 2; ++b) acc[a][b] = (f32x4){0.f, 0.f, 0.f, 0.f};
    float lp[4] = {0.f, 0.f, 0.f, 0.f};

    const int jcol = (jsub << 4) + n16;
    const int j8   = jcol >> 3;
    const int jlo  = jcol & 7;
    const int ksw  = (jq << 2) + quad;

    // Pre-fragmented V base: cblk = cq*2 (+1 for second frag), jblk = tile*2+jq
    // addr = cblk*65536 + jblk*512 + lane*8; per-tile step = 1024 elems.
    const u16* vfp0 = vb + ((size_t)(cq << 1) << 16) + ((size_t)jq << 9)
                         + ((size_t)((quad << 4) + n16) << 3);
    const u16* vfp1 = vfp0 + 65536;

    bf16x8 kreg, vf0, vf1;

    // ---- prologue: S(0) into parity 0; prefetch K(1), V-frags for PV(0) ----
    kreg = *(const bf16x8*)(kb + ((size_t)((jsub << 4) + n16) << 5) + (quad << 3));
    {
        u16* Ps = PsA;
        const f32x4 z = {0.f, 0.f, 0.f, 0.f};
        f32x4 s = __builtin_amdgcn_mfma_f32_16x16x32_bf16(qfrag, kreg, z, 0, 0, 0);
        #pragma unroll
        for (int r = 0; r < 4; ++r) {
            const int qrow = (qsub_s << 4) + (quad << 2) + r;
            float p = exp2f(s[r] - EXP_OFF);
            u32 u = as_u(p) & 0xffff0000u;
            lp[r] += as_f(u);
            Ps[qrow * 64 + ((j8 ^ (qrow & 7)) << 3) + jlo] = (u16)(u >> 16);
        }
        kreg = *(const bf16x8*)(kb + ((size_t)(64 + (jsub << 4) + n16) << 5) + (quad << 3));
        vf0 = *(const bf16x8*)(vfp0);
        vf1 = *(const bf16x8*)(vfp1);
    }
    __syncthreads();

    // ---- main loop: ONE barrier per tile ----
    for (int tile = 1; tile < 64; ++tile) {
        const int par  = tile & 1;
        u16* Psc = PsA + (par << 12);
        u16* Psp = PsA + ((par ^ 1) << 12);

        // PV(tile-1): pa from LDS, vf from prefetched coalesced global regs
        bf16x8 pa[4];
        #pragma unroll
        for (int qs = 0; qs < 4; ++qs) {
            const int qrow = (qs << 4) + n16;
            pa[qs] = *(const bf16x8*)&Psp[qrow * 64 + ((ksw ^ (qrow & 7)) << 3)];
        }
        #pragma unroll
        for (int qs = 0; qs < 4; ++qs) {
            acc[qs][0] = __builtin_amdgcn_mfma_f32_16x16x32_bf16(pa[qs], vf0, acc[qs][0], 0, 0, 0);
            acc[qs][1] = __builtin_amdgcn_mfma_f32_16x16x32_bf16(pa[qs], vf1, acc[qs][1], 0, 0, 0);
        }

        // prefetch V-frags for PV(tile) (used next iteration)
        vf0 = *(const bf16x8*)(vfp0 + ((size_t)tile << 10));
        vf1 = *(const bf16x8*)(vfp1 + ((size_t)tile << 10));

        // S(tile) + softmax + P write
        const f32x4 z = {0.f, 0.f, 0.f, 0.f};
        f32x4 s = __builtin_amdgcn_mfma_f32_16x16x32_bf16(qfrag, kreg, z, 0, 0, 0);
        #pragma unroll
        for (int r = 0; r < 4; ++r) {
            const int qrow = (qsub_s << 4) + (quad << 2) + r;
            float p = exp2f(s[r] - EXP_OFF);
            u32 u = as_u(p) & 0xffff0000u;
            lp[r] += as_f(u);
            Psc[qrow * 64 + ((j8 ^ (qrow & 7)) << 3) + jlo] = (u16)(u >> 16);
        }

        // prefetch K for tile+1
        if (tile < 63) {
            const int j0n = (tile + 1) << 6;
            kreg = *(const bf16x8*)(kb + ((size_t)(j0n + (jsub << 4) + n16) << 5)
                                    + (quad << 3));
        }
        __syncthreads();
    }

    // ---- final PV(63): parity 1, vf holds jblk of tile 63 ----
    {
        u16* Psp = PsA + (1 << 12);
        bf16x8 pa[4];
        #pragma unroll
        for (int qs = 0; qs < 4; ++qs) {
            const int qrow = (qs << 4) + n16;
            pa[qs] = *(const bf16x8*)&Psp[qrow * 64 + ((ksw ^ (qrow & 7)) << 3)];
        }
        #pragma unroll
        for (int qs = 0; qs < 4; ++qs) {
            acc[qs][0] = __builtin_amdgcn_mfma_f32_16x16x32_bf16(pa[qs], vf0, acc[qs][0], 0, 0, 0);
            acc[qs][1] = __builtin_amdgcn_mfma_f32_16x16x32_bf16(pa[qs], vf1, acc[qs][1], 0, 0, 0);
        }
    }

    // ---- l reduction ----
    #pragma unroll
    for (int r = 0; r < 4; ++r) {
        lp[r] += __shfl_xor(lp[r], 1);
        lp[r] += __shfl_xor(lp[r], 2);
        lp[r] += __shfl_xor(lp[r], 4);
        lp[r] += __shfl_xor(lp[r], 8);
    }
    if (n16 == 0) {
        #pragma unroll
        for (int r = 0; r < 4; ++r)
            atomicAdd(&lS[(qsub_s << 4) + (quad << 2) + r], lp[r]);
    }
    __syncthreads();
    if (t < 64) lS[t] = 1.0f / lS[t];
    const bool isf32 = (dtf != 0);

    // ---- epilogue: 4 chunks of 64 c; combine jq-partials in Dbuf, store ----
    for (int chunk = 0; chunk < 4; ++chunk) {
        __syncthreads();   // Dbuf free; rl ready; Ps reads complete (chunk 0)
        if (jq == 1 && (cq >> 1) == chunk) {
            #pragma unroll
            for (int qs = 0; qs < 4; ++qs)
                #pragma unroll
                for (int cs = 0; cs < 2; ++cs)
                    *(f32x4*)&Dbuf[(((cq & 1) << 5) + (cs << 4) + n16) * 68 +
                                   (qs << 4) + (quad << 2)] = acc[qs][cs];
        }
        __syncthreads();
        if (jq == 0 && (cq >> 1) == chunk) {
            #pragma unroll
            for (int qs = 0; qs < 4; ++qs)
                #pragma unroll
                for (int cs = 0; cs < 2; ++cs) {
                    float* p = &Dbuf[(((cq & 1) << 5) + (cs << 4) + n16) * 68 +
                                     (qs << 4) + (quad << 2)];
                    f32x4 d = *(f32x4*)p;
                    d += acc[qs][cs];
                    *(f32x4*)p = d;
                }
        }
        __syncthreads();
        // store: 1024 threads x 4 q
        const int c_l = t >> 4;
        const int qg  = (t & 15) << 2;
        float4 d  = *(float4*)&Dbuf[c_l * 68 + qg];
        float4 rl = *(float4*)&lS[qg];
        const int c_glob = (chunk << 6) + c_l;
        const size_t ob = (((size_t)(n_g * 256 + c_glob)) << 12) + i0 + qg;
        if (isf32) {
            float4 o = make_float4(d.x * rl.x, d.y * rl.y, d.z * rl.z, d.w * rl.w);
            *(float4*)((float*)out + ob) = o;
        } else {
            union { uint2 v; u16 h[4]; } o;
            o.h[0] = f2bf(d.x * rl.x);
            o.h[1] = f2bf(d.y * rl.y);
            o.h[2] = f2bf(d.z * rl.z);
            o.h[3] = f2bf(d.w * rl.w);
            *(uint2*)((u16*)out + ob) = o.v;
        }
    }
}

extern "C" void kernel_launch(void* const* d_in, const int* in_sizes, int n_in,
                              void* d_out, int out_size, void* d_ws, size_t ws_size,
                              hipStream_t stream)
{
    const void* x  = d_in[0];
    const void* Wq = d_in[1];
    const void* bq = d_in[2];
    const void* Wk = d_in[3];
    const void* bk = d_in[4];
    const void* Wv = d_in[5];
    const void* bv = d_in[6];

    const size_t full_need = (size_t)(4u * 4096u) * (32 + 32 + 256) * 2; // 10 MB
    if (ws_size >= full_need) {
        u16* qws = (u16*)d_ws;
        u16* kws = qws + (size_t)4 * 4096 * 32;
        u16* vws = kws + (size_t)4 * 4096 * 32;
        qkv_proj_kernel<<<dim3(64, 5, 4), dim3(256), 0, stream>>>(
            x, Wq, bq, Wk, bk, Wv, bv, qws, kws, vws, 0);
        flash_mfma6<<<dim3(256), dim3(1024), 0, stream>>>(
            qws, kws, vws, d_out, x, 0, 2);
    } else {
        u16* qws = (u16*)d_ws;
        u16* kws = qws + (size_t)4096 * 32;
        u16* vws = kws + (size_t)4096 * 32;
        for (int n = 0; n < 4; ++n) {
            qkv_proj_kernel<<<dim3(64, 5, 1), dim3(256), 0, stream>>>(
                x, Wq, bq, Wk, bk, Wv, bv, qws, kws, vws, n);
            flash_mfma6<<<dim3(64), dim3(1024), 0, stream>>>(
                qws, kws, vws, d_out, x, n, 0);
        }
    }
}